// Round 3
// baseline (435.730 us; speedup 1.0000x reference)
//
#include <hip/hip_runtime.h>
#include <hip/hip_bf16.h>
#include <cstdint>

// Problem constants: B=2, L=2048, D=1024, H=16, HD=64
#define LEN   2048
#define DMODEL 1024
#define NH    16
#define HD    64
#define BH    32          // B*NH
#define MROWS 4096        // B*LEN

typedef __attribute__((ext_vector_type(8))) short bf16x8;
typedef __attribute__((ext_vector_type(4))) float f32x4;
typedef unsigned int u32;

__device__ __forceinline__ void gload_lds16(const void* g, void* l) {
    __builtin_amdgcn_global_load_lds(
        (const __attribute__((address_space(1))) u32*)g,
        (__attribute__((address_space(3))) u32*)l, 16, 0, 0);
}

// ---------------------------------------------------------------- cast f32->bf16
__global__ void cast_f32_bf16_k(const float* __restrict__ in,
                                __hip_bfloat16* __restrict__ out, int n4) {
    int stride = gridDim.x * blockDim.x;
    for (int i = blockIdx.x * blockDim.x + threadIdx.x; i < n4; i += stride) {
        float4 v = reinterpret_cast<const float4*>(in)[i];
        __hip_bfloat16 h0 = __float2bfloat16(v.x);
        __hip_bfloat16 h1 = __float2bfloat16(v.y);
        __hip_bfloat16 h2 = __float2bfloat16(v.z);
        __hip_bfloat16 h3 = __float2bfloat16(v.w);
        ushort4 p;
        p.x = *reinterpret_cast<unsigned short*>(&h0);
        p.y = *reinterpret_cast<unsigned short*>(&h1);
        p.z = *reinterpret_cast<unsigned short*>(&h2);
        p.w = *reinterpret_cast<unsigned short*>(&h3);
        reinterpret_cast<ushort4*>(out)[i] = p;
    }
}

// ---------------------------------------------------------------- fused QKV GEMM
// C = x @ Wqkv^T + b ; A [4096][1024] bf16, Bw [3072][1024] bf16 (rows = out neuron).
// 128x128 tile, BK=32, 4 waves (2x2), each wave 64x64 = 4x4 frags of 16x16x32.
// Epilogue: sel = n>>10 : 0 -> Q [bh][l][hd], 1 -> K [bh][l][hd], 2 -> V^T [bh][hd][l]
__global__ __launch_bounds__(256) void gemm_qkv(
    const __hip_bfloat16* __restrict__ A,
    const __hip_bfloat16* __restrict__ Bw,
    const float* __restrict__ bq, const float* __restrict__ bk,
    const float* __restrict__ bv,
    __hip_bfloat16* __restrict__ Qb, __hip_bfloat16* __restrict__ Kb,
    __hip_bfloat16* __restrict__ VTb) {
    constexpr int Kd = DMODEL;
    __shared__ __hip_bfloat16 As[128 * 32];
    __shared__ __hip_bfloat16 Bs[128 * 32];
    const int tid = threadIdx.x;
    const int wave = tid >> 6, lane = tid & 63;
    const int lg = lane >> 4, lr = lane & 15;
    const int wr = wave >> 1, wc = wave & 1;
    const int by = blockIdx.y, bx = blockIdx.x;
    const __hip_bfloat16* Ab = A + (size_t)by * 128 * Kd;
    const __hip_bfloat16* Bb = Bw + (size_t)bx * 128 * Kd;
    f32x4 acc[4][4] = {};
    for (int kt = 0; kt < Kd / 32; ++kt) {
#pragma unroll
        for (int i = 0; i < 2; ++i) {
            int c = tid + i * 256;
            int row = c >> 2, c4 = c & 3;
            gload_lds16(Ab + (size_t)row * Kd + kt * 32 + c4 * 8, &As[c * 8]);
        }
#pragma unroll
        for (int i = 0; i < 2; ++i) {
            int c = tid + i * 256;
            int row = c >> 2, c4 = c & 3;
            gload_lds16(Bb + (size_t)row * Kd + kt * 32 + c4 * 8, &Bs[c * 8]);
        }
        __syncthreads();
        bf16x8 af[4], bfr[4];
#pragma unroll
        for (int m = 0; m < 4; ++m)
            af[m] = *(const bf16x8*)&As[(wr * 64 + m * 16 + lr) * 32 + lg * 8];
#pragma unroll
        for (int n = 0; n < 4; ++n)
            bfr[n] = *(const bf16x8*)&Bs[(wc * 64 + n * 16 + lr) * 32 + lg * 8];
#pragma unroll
        for (int m = 0; m < 4; ++m)
#pragma unroll
            for (int n = 0; n < 4; ++n)
                acc[m][n] = __builtin_amdgcn_mfma_f32_16x16x32_bf16(
                    af[m], bfr[n], acc[m][n], 0, 0, 0);
        __syncthreads();
    }
    const int sel = (bx * 128) >> 10;  // block-uniform 0/1/2
    const float* bp = sel == 0 ? bq : (sel == 1 ? bk : bv);
    __hip_bfloat16* dst = sel == 0 ? Qb : (sel == 1 ? Kb : VTb);
#pragma unroll
    for (int m = 0; m < 4; ++m)
#pragma unroll
        for (int n = 0; n < 4; ++n)
#pragma unroll
            for (int r = 0; r < 4; ++r) {
                int gm = by * 128 + wr * 64 + m * 16 + lg * 4 + r;
                int gn = bx * 128 + wc * 64 + n * 16 + lr;
                int nn = gn & (DMODEL - 1);
                float v = acc[m][n][r] + bp[nn];
                int bb = gm >> 11, l = gm & (LEN - 1);
                int h = nn >> 6, hd = nn & (HD - 1);
                size_t addr = (sel < 2)
                    ? ((((size_t)bb * NH + h) * LEN + l) * HD + hd)
                    : ((((size_t)bb * NH + h) * HD + hd) * LEN + l);
                dst[addr] = __float2bfloat16(v);
            }
}

// ---------------------------------------------------------------- flash attention
// grid (L/64, BH). 4 waves; wave owns 16 q rows. KT=64 keys/iter.
// K, V^T read directly from global (L2-resident, 32x reuse per head).
__global__ __launch_bounds__(256) void attn_fwd(
    const __hip_bfloat16* __restrict__ Qb,   // [BH][L][HD]
    const __hip_bfloat16* __restrict__ Kb,   // [BH][L][HD]
    const __hip_bfloat16* __restrict__ VTb,  // [BH][HD][L]
    __hip_bfloat16* __restrict__ Ob) {       // [B][L][D]
    const int bh = blockIdx.y;
    const int b = bh >> 4, h = bh & (NH - 1);
    const int wave = threadIdx.x >> 6, lane = threadIdx.x & 63;
    const int lg = lane >> 4, lr = lane & 15;
    const int qw = blockIdx.x * 64 + wave * 16;
    const __hip_bfloat16* Qp = Qb + ((size_t)bh * LEN + qw) * HD;
    const __hip_bfloat16* Kp = Kb + (size_t)bh * LEN * HD;
    const __hip_bfloat16* Vp = VTb + (size_t)bh * HD * LEN;

    bf16x8 qf[2];
    qf[0] = *(const bf16x8*)(Qp + lr * HD + lg * 8);
    qf[1] = *(const bf16x8*)(Qp + lr * HD + 32 + lg * 8);

    float m_i[4] = {-INFINITY, -INFINITY, -INFINITY, -INFINITY};
    float l_i[4] = {0.f, 0.f, 0.f, 0.f};
    f32x4 o[4] = {};

    __shared__ __hip_bfloat16 Plds[4][16][72];  // per-wave P tile, padded rows
    __hip_bfloat16* pl = &Plds[wave][0][0];

    for (int kt = 0; kt < LEN / 64; ++kt) {
        const __hip_bfloat16* Kt = Kp + (size_t)kt * 64 * HD;
        f32x4 s[4] = {};
#pragma unroll
        for (int kk = 0; kk < 2; ++kk) {
#pragma unroll
            for (int n = 0; n < 4; ++n) {
                bf16x8 kf = *(const bf16x8*)(Kt + (size_t)(n * 16 + lr) * HD +
                                             kk * 32 + lg * 8);
                s[n] = __builtin_amdgcn_mfma_f32_16x16x32_bf16(qf[kk], kf, s[n],
                                                               0, 0, 0);
            }
        }
        // --- online softmax (rows = lg*4 + r, cols = n*16 + lr) ---
        float p[4][4];
#pragma unroll
        for (int r = 0; r < 4; ++r) {
            float v0 = fmaxf(fmaxf(s[0][r], s[1][r]), fmaxf(s[2][r], s[3][r]));
            v0 *= 0.125f;
#pragma unroll
            for (int off = 1; off < 16; off <<= 1)
                v0 = fmaxf(v0, __shfl_xor(v0, off, 64));
            float mnew = fmaxf(m_i[r], v0);
            float corr = __expf(m_i[r] - mnew);
            m_i[r] = mnew;
            l_i[r] *= corr;
#pragma unroll
            for (int n = 0; n < 4; ++n) o[n][r] *= corr;
            float ps = 0.f;
#pragma unroll
            for (int n = 0; n < 4; ++n) {
                float pv = __expf(s[n][r] * 0.125f - mnew);
                p[r][n] = pv;
                ps += pv;
            }
#pragma unroll
            for (int off = 1; off < 16; off <<= 1)
                ps += __shfl_xor(ps, off, 64);
            l_i[r] += ps;
        }
        // --- stage P (bf16) into per-wave LDS ---
#pragma unroll
        for (int r = 0; r < 4; ++r)
#pragma unroll
            for (int n = 0; n < 4; ++n)
                pl[(lg * 4 + r) * 72 + n * 16 + lr] = __float2bfloat16(p[r][n]);
        asm volatile("" ::: "memory");  // keep write->read order; LDS is in-order per wave
        // --- PV: O += P @ V ---
#pragma unroll
        for (int kk = 0; kk < 2; ++kk) {
            bf16x8 pa = *(const bf16x8*)&pl[lr * 72 + kk * 32 + lg * 8];
#pragma unroll
            for (int n = 0; n < 4; ++n) {
                bf16x8 vf = *(const bf16x8*)(Vp + (size_t)(n * 16 + lr) * LEN +
                                             kt * 64 + kk * 32 + lg * 8);
                o[n] = __builtin_amdgcn_mfma_f32_16x16x32_bf16(pa, vf, o[n],
                                                               0, 0, 0);
            }
        }
    }
    float inv[4];
#pragma unroll
    for (int r = 0; r < 4; ++r) inv[r] = 1.f / l_i[r];
#pragma unroll
    for (int n = 0; n < 4; ++n)
#pragma unroll
        for (int r = 0; r < 4; ++r) {
            int gq = qw + lg * 4 + r;
            int gd = h * HD + n * 16 + lr;
            Ob[((size_t)b * LEN + gq) * DMODEL + gd] =
                __float2bfloat16(o[n][r] * inv[r]);
        }
}

// ---------------------------------------------------------------- output GEMM
// out = Ob @ wo^T + bo, f32 out. 64x128 tile (grid 512 for occupancy), BK=32.
__global__ __launch_bounds__(256) void gemm_out(
    const __hip_bfloat16* __restrict__ A,    // [4096][1024]
    const __hip_bfloat16* __restrict__ Bw,   // [1024][1024]
    const float* __restrict__ bo, float* __restrict__ out) {
    constexpr int Kd = DMODEL, N = DMODEL;
    __shared__ __hip_bfloat16 As[64 * 32];
    __shared__ __hip_bfloat16 Bs[128 * 32];
    const int tid = threadIdx.x;
    const int wave = tid >> 6, lane = tid & 63;
    const int lg = lane >> 4, lr = lane & 15;
    const int wr = wave >> 1, wc = wave & 1;  // wave tile 32x64
    const int by = blockIdx.y, bx = blockIdx.x;
    const __hip_bfloat16* Ab = A + (size_t)by * 64 * Kd;
    const __hip_bfloat16* Bb = Bw + (size_t)bx * 128 * Kd;
    f32x4 acc[2][4] = {};
    for (int kt = 0; kt < Kd / 32; ++kt) {
        {
            int c = tid;  // 256 chunks cover 64x32
            int row = c >> 2, c4 = c & 3;
            gload_lds16(Ab + (size_t)row * Kd + kt * 32 + c4 * 8, &As[c * 8]);
        }
#pragma unroll
        for (int i = 0; i < 2; ++i) {
            int c = tid + i * 256;
            int row = c >> 2, c4 = c & 3;
            gload_lds16(Bb + (size_t)row * Kd + kt * 32 + c4 * 8, &Bs[c * 8]);
        }
        __syncthreads();
        bf16x8 af[2], bfr[4];
#pragma unroll
        for (int m = 0; m < 2; ++m)
            af[m] = *(const bf16x8*)&As[(wr * 32 + m * 16 + lr) * 32 + lg * 8];
#pragma unroll
        for (int n = 0; n < 4; ++n)
            bfr[n] = *(const bf16x8*)&Bs[(wc * 64 + n * 16 + lr) * 32 + lg * 8];
#pragma unroll
        for (int m = 0; m < 2; ++m)
#pragma unroll
            for (int n = 0; n < 4; ++n)
                acc[m][n] = __builtin_amdgcn_mfma_f32_16x16x32_bf16(
                    af[m], bfr[n], acc[m][n], 0, 0, 0);
        __syncthreads();
    }
#pragma unroll
    for (int m = 0; m < 2; ++m)
#pragma unroll
        for (int n = 0; n < 4; ++n)
#pragma unroll
            for (int r = 0; r < 4; ++r) {
                int gm = by * 64 + wr * 32 + m * 16 + lg * 4 + r;
                int gn = bx * 128 + wc * 64 + n * 16 + lr;
                out[(size_t)gm * N + gn] = acc[m][n][r] + bo[gn];
            }
}

// ---------------------------------------------------------------- launch
extern "C" void kernel_launch(void* const* d_in, const int* in_sizes, int n_in,
                              void* d_out, int out_size, void* d_ws, size_t ws_size,
                              hipStream_t stream) {
    const float* x  = (const float*)d_in[0];
    const float* wq = (const float*)d_in[1];
    const float* bq = (const float*)d_in[2];
    const float* wk = (const float*)d_in[3];
    const float* bk = (const float*)d_in[4];
    const float* wv = (const float*)d_in[5];
    const float* bv = (const float*)d_in[6];
    const float* wo = (const float*)d_in[7];
    const float* bo = (const float*)d_in[8];

    char* ws = (char*)d_ws;
    __hip_bfloat16* x_bf  = (__hip_bfloat16*)(ws);                    // 8 MB
    __hip_bfloat16* wqkv  = (__hip_bfloat16*)(ws + (8u  << 20));      // 6 MB
    __hip_bfloat16* wo_bf = (__hip_bfloat16*)(ws + (14u << 20));      // 2 MB
    __hip_bfloat16* Qb    = (__hip_bfloat16*)(ws + (16u << 20));      // 8 MB
    __hip_bfloat16* Kb    = (__hip_bfloat16*)(ws + (24u << 20));      // 8 MB
    __hip_bfloat16* VTb   = (__hip_bfloat16*)(ws + (32u << 20));      // 8 MB
    __hip_bfloat16* Ob    = (__hip_bfloat16*)(ws + (40u << 20));      // 8 MB

    cast_f32_bf16_k<<<1024, 256, 0, stream>>>(x, x_bf, (MROWS * DMODEL) / 4);
    cast_f32_bf16_k<<<512, 256, 0, stream>>>(wq, wqkv, (DMODEL * DMODEL) / 4);
    cast_f32_bf16_k<<<512, 256, 0, stream>>>(wk, wqkv + (1u << 20), (DMODEL * DMODEL) / 4);
    cast_f32_bf16_k<<<512, 256, 0, stream>>>(wv, wqkv + (2u << 20), (DMODEL * DMODEL) / 4);
    cast_f32_bf16_k<<<512, 256, 0, stream>>>(wo, wo_bf, (DMODEL * DMODEL) / 4);

    gemm_qkv<<<dim3(24, 32), 256, 0, stream>>>(x_bf, wqkv, bq, bk, bv, Qb, Kb, VTb);
    attn_fwd<<<dim3(LEN / 64, BH), 256, 0, stream>>>(Qb, Kb, VTb, Ob);
    gemm_out<<<dim3(8, 64), 256, 0, stream>>>(Ob, wo_bf, bo, (float*)d_out);
}

// Round 4
// 271.317 us; speedup vs baseline: 1.6060x; 1.6060x over previous
//
#include <hip/hip_runtime.h>
#include <hip/hip_bf16.h>
#include <cstdint>

// Problem constants: B=2, L=2048, D=1024, H=16, HD=64
#define LEN   2048
#define DMODEL 1024
#define NH    16
#define HD    64
#define BH    32          // B*NH
#define MROWS 4096        // B*LEN

typedef __attribute__((ext_vector_type(8))) short bf16x8;
typedef __attribute__((ext_vector_type(4))) float f32x4;
typedef unsigned int u32;

__device__ __forceinline__ void gload_lds16(const void* g, void* l) {
    __builtin_amdgcn_global_load_lds(
        (const __attribute__((address_space(1))) u32*)g,
        (__attribute__((address_space(3))) u32*)l, 16, 0, 0);
}

// ---------------------------------------------------------------- cast f32->bf16
__global__ void cast_f32_bf16_k(const float* __restrict__ in,
                                __hip_bfloat16* __restrict__ out, int n4) {
    int stride = gridDim.x * blockDim.x;
    for (int i = blockIdx.x * blockDim.x + threadIdx.x; i < n4; i += stride) {
        float4 v = reinterpret_cast<const float4*>(in)[i];
        __hip_bfloat16 h0 = __float2bfloat16(v.x);
        __hip_bfloat16 h1 = __float2bfloat16(v.y);
        __hip_bfloat16 h2 = __float2bfloat16(v.z);
        __hip_bfloat16 h3 = __float2bfloat16(v.w);
        ushort4 p;
        p.x = *reinterpret_cast<unsigned short*>(&h0);
        p.y = *reinterpret_cast<unsigned short*>(&h1);
        p.z = *reinterpret_cast<unsigned short*>(&h2);
        p.w = *reinterpret_cast<unsigned short*>(&h3);
        reinterpret_cast<ushort4*>(out)[i] = p;
    }
}

// ---------------------------------------------------------------- fused QKV GEMM
// (unchanged from round 3 — verified correct; attn is the bottleneck this round)
__global__ __launch_bounds__(256) void gemm_qkv(
    const __hip_bfloat16* __restrict__ A,
    const __hip_bfloat16* __restrict__ Bw,
    const float* __restrict__ bq, const float* __restrict__ bk,
    const float* __restrict__ bv,
    __hip_bfloat16* __restrict__ Qb, __hip_bfloat16* __restrict__ Kb,
    __hip_bfloat16* __restrict__ VTb) {
    constexpr int Kd = DMODEL;
    __shared__ __hip_bfloat16 As[128 * 32];
    __shared__ __hip_bfloat16 Bs[128 * 32];
    const int tid = threadIdx.x;
    const int wave = tid >> 6, lane = tid & 63;
    const int lg = lane >> 4, lr = lane & 15;
    const int wr = wave >> 1, wc = wave & 1;
    const int by = blockIdx.y, bx = blockIdx.x;
    const __hip_bfloat16* Ab = A + (size_t)by * 128 * Kd;
    const __hip_bfloat16* Bb = Bw + (size_t)bx * 128 * Kd;
    f32x4 acc[4][4] = {};
    for (int kt = 0; kt < Kd / 32; ++kt) {
#pragma unroll
        for (int i = 0; i < 2; ++i) {
            int c = tid + i * 256;
            int row = c >> 2, c4 = c & 3;
            gload_lds16(Ab + (size_t)row * Kd + kt * 32 + c4 * 8, &As[c * 8]);
        }
#pragma unroll
        for (int i = 0; i < 2; ++i) {
            int c = tid + i * 256;
            int row = c >> 2, c4 = c & 3;
            gload_lds16(Bb + (size_t)row * Kd + kt * 32 + c4 * 8, &Bs[c * 8]);
        }
        __syncthreads();
        bf16x8 af[4], bfr[4];
#pragma unroll
        for (int m = 0; m < 4; ++m)
            af[m] = *(const bf16x8*)&As[(wr * 64 + m * 16 + lr) * 32 + lg * 8];
#pragma unroll
        for (int n = 0; n < 4; ++n)
            bfr[n] = *(const bf16x8*)&Bs[(wc * 64 + n * 16 + lr) * 32 + lg * 8];
#pragma unroll
        for (int m = 0; m < 4; ++m)
#pragma unroll
            for (int n = 0; n < 4; ++n)
                acc[m][n] = __builtin_amdgcn_mfma_f32_16x16x32_bf16(
                    af[m], bfr[n], acc[m][n], 0, 0, 0);
        __syncthreads();
    }
    const int sel = (bx * 128) >> 10;  // block-uniform 0/1/2
    const float* bp = sel == 0 ? bq : (sel == 1 ? bk : bv);
    __hip_bfloat16* dst = sel == 0 ? Qb : (sel == 1 ? Kb : VTb);
#pragma unroll
    for (int m = 0; m < 4; ++m)
#pragma unroll
        for (int n = 0; n < 4; ++n)
#pragma unroll
            for (int r = 0; r < 4; ++r) {
                int gm = by * 128 + wr * 64 + m * 16 + lg * 4 + r;
                int gn = bx * 128 + wc * 64 + n * 16 + lr;
                int nn = gn & (DMODEL - 1);
                float v = acc[m][n][r] + bp[nn];
                int bb = gm >> 11, l = gm & (LEN - 1);
                int h = nn >> 6, hd = nn & (HD - 1);
                size_t addr = (sel < 2)
                    ? ((((size_t)bb * NH + h) * LEN + l) * HD + hd)
                    : ((((size_t)bb * NH + h) * HD + hd) * LEN + l);
                dst[addr] = __float2bfloat16(v);
            }
}

// ---------------------------------------------------------------- flash attention
// grid: 1024 blocks 1D (XCD-swizzled -> (bh, qtile)). 4 waves x 16 q-rows.
// K/V tiles (64 keys) staged cooperatively in XOR-swizzled LDS, double-buffered,
// prefetch issued at top of iter, one __syncthreads per iter (T3 minimum).
__global__ __launch_bounds__(256) void attn_fwd(
    const __hip_bfloat16* __restrict__ Qb,   // [BH][L][HD]
    const __hip_bfloat16* __restrict__ Kb,   // [BH][L][HD]
    const __hip_bfloat16* __restrict__ VTb,  // [BH][HD][L]
    __hip_bfloat16* __restrict__ Ob) {       // [B][L][D]
    // XCD swizzle: 1024 blocks = 8 XCDs x 128; consecutive wg share bh on one XCD
    const int lin = blockIdx.x;
    const int wg = (lin & 7) * 128 + (lin >> 3);   // bijective (1024 = 8*128)
    const int bh = wg >> 5;          // 0..31
    const int qt = wg & 31;          // 0..31
    const int b = bh >> 4, h = bh & (NH - 1);
    const int tid = threadIdx.x;
    const int wave = tid >> 6, lane = tid & 63;
    const int lg = lane >> 4, lr = lane & 15;
    const int sw = lr & 7;           // row-XOR swizzle key for fragment reads
    const int qw = qt * 64 + wave * 16;
    const __hip_bfloat16* Qp = Qb + ((size_t)bh * LEN + qw) * HD;
    const __hip_bfloat16* Kp = Kb + (size_t)bh * LEN * HD;
    const __hip_bfloat16* Vp = VTb + (size_t)bh * HD * LEN;

    // K/V tiles in LDS: [2 bufs][64 rows][64 elems], rows 128B.
    // Linear dest for global_load_lds; source pre-swizzled chunk jj^(row&7);
    // reads apply the same XOR (rule #21 both-sides involution).
    __shared__ __hip_bfloat16 Ks[2][64 * 64];
    __shared__ __hip_bfloat16 Vs[2][64 * 64];
    __shared__ __hip_bfloat16 Plds[4][16][72];
    __hip_bfloat16* pl = &Plds[wave][0][0];

    // staging geometry: 512 chunks of 16B per tile; this thread owns c0,c1
    const int c0 = tid, c1 = tid + 256;
    const int r0 = c0 >> 3, j0 = (c0 & 7) ^ (r0 & 7);
    const int r1 = c1 >> 3, j1 = (c1 & 7) ^ (r1 & 7);
    const __hip_bfloat16* kg0 = Kp + (size_t)r0 * HD + j0 * 8;
    const __hip_bfloat16* kg1 = Kp + (size_t)r1 * HD + j1 * 8;
    const __hip_bfloat16* vg0 = Vp + (size_t)r0 * LEN + j0 * 8;
    const __hip_bfloat16* vg1 = Vp + (size_t)r1 * LEN + j1 * 8;

    bf16x8 qf[2];
    qf[0] = *(const bf16x8*)(Qp + lr * HD + lg * 8);
    qf[1] = *(const bf16x8*)(Qp + lr * HD + 32 + lg * 8);

    float m_i[4] = {-INFINITY, -INFINITY, -INFINITY, -INFINITY};
    float l_i[4] = {0.f, 0.f, 0.f, 0.f};
    f32x4 o[4] = {};

    // prologue: stage tile 0 into buffer 0
    gload_lds16(kg0, &Ks[0][c0 * 8]);
    gload_lds16(kg1, &Ks[0][c1 * 8]);
    gload_lds16(vg0, &Vs[0][c0 * 8]);
    gload_lds16(vg1, &Vs[0][c1 * 8]);
    __syncthreads();

    constexpr int NT = LEN / 64;
    for (int kt = 0; kt < NT; ++kt) {
        const int cb = kt & 1, nb = cb ^ 1;
        if (kt + 1 < NT) {  // prefetch next tile (K advances 64*HD, V 64 cols)
            size_t ko = (size_t)(kt + 1) * 64 * HD;
            size_t vo = (size_t)(kt + 1) * 64;
            gload_lds16(kg0 + ko, &Ks[nb][c0 * 8]);
            gload_lds16(kg1 + ko, &Ks[nb][c1 * 8]);
            gload_lds16(vg0 + vo, &Vs[nb][c0 * 8]);
            gload_lds16(vg1 + vo, &Vs[nb][c1 * 8]);
        }
        const __hip_bfloat16* ks = Ks[cb];
        const __hip_bfloat16* vs = Vs[cb];
        // --- QK^T from LDS (swizzled reads) ---
        f32x4 s[4] = {};
#pragma unroll
        for (int kk = 0; kk < 2; ++kk) {
#pragma unroll
            for (int n = 0; n < 4; ++n) {
                int krow = n * 16 + lr;
                bf16x8 kf = *(const bf16x8*)&ks[krow * 64 +
                                                (((kk << 2) + lg) ^ sw) * 8];
                s[n] = __builtin_amdgcn_mfma_f32_16x16x32_bf16(qf[kk], kf, s[n],
                                                               0, 0, 0);
            }
        }
        // --- online softmax (rows = lg*4 + r, cols = n*16 + lr) ---
        float p[4][4];
#pragma unroll
        for (int r = 0; r < 4; ++r) {
            float v0 = fmaxf(fmaxf(s[0][r], s[1][r]), fmaxf(s[2][r], s[3][r]));
            v0 *= 0.125f;
#pragma unroll
            for (int off = 1; off < 16; off <<= 1)
                v0 = fmaxf(v0, __shfl_xor(v0, off, 64));
            float mnew = fmaxf(m_i[r], v0);
            float corr = __expf(m_i[r] - mnew);
            m_i[r] = mnew;
            l_i[r] *= corr;
#pragma unroll
            for (int n = 0; n < 4; ++n) o[n][r] *= corr;
            float ps = 0.f;
#pragma unroll
            for (int n = 0; n < 4; ++n) {
                float pv = __expf(s[n][r] * 0.125f - mnew);
                p[r][n] = pv;
                ps += pv;
            }
#pragma unroll
            for (int off = 1; off < 16; off <<= 1)
                ps += __shfl_xor(ps, off, 64);
            l_i[r] += ps;
        }
        // --- stage P (bf16) into per-wave LDS (wave-local, no barrier) ---
#pragma unroll
        for (int r = 0; r < 4; ++r)
#pragma unroll
            for (int n = 0; n < 4; ++n)
                pl[(lg * 4 + r) * 72 + n * 16 + lr] = __float2bfloat16(p[r][n]);
        asm volatile("" ::: "memory");
        // --- PV from LDS V (swizzled reads) ---
#pragma unroll
        for (int kk = 0; kk < 2; ++kk) {
            bf16x8 pa = *(const bf16x8*)&pl[lr * 72 + kk * 32 + lg * 8];
#pragma unroll
            for (int n = 0; n < 4; ++n) {
                int vrow = n * 16 + lr;
                bf16x8 vf = *(const bf16x8*)&vs[vrow * 64 +
                                                (((kk << 2) + lg) ^ sw) * 8];
                o[n] = __builtin_amdgcn_mfma_f32_16x16x32_bf16(pa, vf, o[n],
                                                               0, 0, 0);
            }
        }
        __syncthreads();  // drains this wave's prefetch (vmcnt0) + publishes nb
    }
    float inv[4];
#pragma unroll
    for (int r = 0; r < 4; ++r) inv[r] = 1.f / l_i[r];
#pragma unroll
    for (int n = 0; n < 4; ++n)
#pragma unroll
        for (int r = 0; r < 4; ++r) {
            int gq = qw + lg * 4 + r;
            int gd = h * HD + n * 16 + lr;
            Ob[((size_t)b * LEN + gq) * DMODEL + gd] =
                __float2bfloat16(o[n][r] * inv[r]);
        }
}

// ---------------------------------------------------------------- output GEMM
__global__ __launch_bounds__(256) void gemm_out(
    const __hip_bfloat16* __restrict__ A,    // [4096][1024]
    const __hip_bfloat16* __restrict__ Bw,   // [1024][1024]
    const float* __restrict__ bo, float* __restrict__ out) {
    constexpr int Kd = DMODEL, N = DMODEL;
    __shared__ __hip_bfloat16 As[64 * 32];
    __shared__ __hip_bfloat16 Bs[128 * 32];
    const int tid = threadIdx.x;
    const int wave = tid >> 6, lane = tid & 63;
    const int lg = lane >> 4, lr = lane & 15;
    const int wr = wave >> 1, wc = wave & 1;  // wave tile 32x64
    const int by = blockIdx.y, bx = blockIdx.x;
    const __hip_bfloat16* Ab = A + (size_t)by * 64 * Kd;
    const __hip_bfloat16* Bb = Bw + (size_t)bx * 128 * Kd;
    f32x4 acc[2][4] = {};
    for (int kt = 0; kt < Kd / 32; ++kt) {
        {
            int c = tid;
            int row = c >> 2, c4 = c & 3;
            gload_lds16(Ab + (size_t)row * Kd + kt * 32 + c4 * 8, &As[c * 8]);
        }
#pragma unroll
        for (int i = 0; i < 2; ++i) {
            int c = tid + i * 256;
            int row = c >> 2, c4 = c & 3;
            gload_lds16(Bb + (size_t)row * Kd + kt * 32 + c4 * 8, &Bs[c * 8]);
        }
        __syncthreads();
        bf16x8 af[2], bfr[4];
#pragma unroll
        for (int m = 0; m < 2; ++m)
            af[m] = *(const bf16x8*)&As[(wr * 32 + m * 16 + lr) * 32 + lg * 8];
#pragma unroll
        for (int n = 0; n < 4; ++n)
            bfr[n] = *(const bf16x8*)&Bs[(wc * 64 + n * 16 + lr) * 32 + lg * 8];
#pragma unroll
        for (int m = 0; m < 2; ++m)
#pragma unroll
            for (int n = 0; n < 4; ++n)
                acc[m][n] = __builtin_amdgcn_mfma_f32_16x16x32_bf16(
                    af[m], bfr[n], acc[m][n], 0, 0, 0);
        __syncthreads();
    }
#pragma unroll
    for (int m = 0; m < 2; ++m)
#pragma unroll
        for (int n = 0; n < 4; ++n)
#pragma unroll
            for (int r = 0; r < 4; ++r) {
                int gm = by * 64 + wr * 32 + m * 16 + lg * 4 + r;
                int gn = bx * 128 + wc * 64 + n * 16 + lr;
                out[(size_t)gm * N + gn] = acc[m][n][r] + bo[gn];
            }
}

// ---------------------------------------------------------------- launch
extern "C" void kernel_launch(void* const* d_in, const int* in_sizes, int n_in,
                              void* d_out, int out_size, void* d_ws, size_t ws_size,
                              hipStream_t stream) {
    const float* x  = (const float*)d_in[0];
    const float* wq = (const float*)d_in[1];
    const float* bq = (const float*)d_in[2];
    const float* wk = (const float*)d_in[3];
    const float* bk = (const float*)d_in[4];
    const float* wv = (const float*)d_in[5];
    const float* bv = (const float*)d_in[6];
    const float* wo = (const float*)d_in[7];
    const float* bo = (const float*)d_in[8];

    char* ws = (char*)d_ws;
    __hip_bfloat16* x_bf  = (__hip_bfloat16*)(ws);                    // 8 MB
    __hip_bfloat16* wqkv  = (__hip_bfloat16*)(ws + (8u  << 20));      // 6 MB
    __hip_bfloat16* wo_bf = (__hip_bfloat16*)(ws + (14u << 20));      // 2 MB
    __hip_bfloat16* Qb    = (__hip_bfloat16*)(ws + (16u << 20));      // 8 MB
    __hip_bfloat16* Kb    = (__hip_bfloat16*)(ws + (24u << 20));      // 8 MB
    __hip_bfloat16* VTb   = (__hip_bfloat16*)(ws + (32u << 20));      // 8 MB
    __hip_bfloat16* Ob    = (__hip_bfloat16*)(ws + (40u << 20));      // 8 MB

    cast_f32_bf16_k<<<1024, 256, 0, stream>>>(x, x_bf, (MROWS * DMODEL) / 4);
    cast_f32_bf16_k<<<512, 256, 0, stream>>>(wq, wqkv, (DMODEL * DMODEL) / 4);
    cast_f32_bf16_k<<<512, 256, 0, stream>>>(wk, wqkv + (1u << 20), (DMODEL * DMODEL) / 4);
    cast_f32_bf16_k<<<512, 256, 0, stream>>>(wv, wqkv + (2u << 20), (DMODEL * DMODEL) / 4);
    cast_f32_bf16_k<<<512, 256, 0, stream>>>(wo, wo_bf, (DMODEL * DMODEL) / 4);

    gemm_qkv<<<dim3(24, 32), 256, 0, stream>>>(x_bf, wqkv, bq, bk, bv, Qb, Kb, VTb);
    attn_fwd<<<1024, 256, 0, stream>>>(Qb, Kb, VTb, Ob);
    gemm_out<<<dim3(8, 64), 256, 0, stream>>>(Ob, wo_bf, bo, (float*)d_out);
}

// Round 5
// 245.210 us; speedup vs baseline: 1.7770x; 1.1065x over previous
//
#include <hip/hip_runtime.h>
#include <hip/hip_bf16.h>
#include <cstdint>

// Problem constants: B=2, L=2048, D=1024, H=16, HD=64
#define LEN   2048
#define DMODEL 1024
#define NH    16
#define HD    64
#define BH    32          // B*NH
#define MROWS 4096        // B*LEN

typedef __attribute__((ext_vector_type(8))) short bf16x8;
typedef __attribute__((ext_vector_type(4))) float f32x4;
typedef unsigned int u32;

__device__ __forceinline__ void gload_lds16(const void* g, void* l) {
    __builtin_amdgcn_global_load_lds(
        (const __attribute__((address_space(1))) u32*)g,
        (__attribute__((address_space(3))) u32*)l, 16, 0, 0);
}

__device__ __forceinline__ unsigned short bfb(float f) {
    __hip_bfloat16 h = __float2bfloat16(f);
    return *reinterpret_cast<unsigned short*>(&h);
}

// ---------------------------------------------------------------- cast f32->bf16
__global__ void cast_f32_bf16_k(const float* __restrict__ in,
                                __hip_bfloat16* __restrict__ out, int n4) {
    int stride = gridDim.x * blockDim.x;
    for (int i = blockIdx.x * blockDim.x + threadIdx.x; i < n4; i += stride) {
        float4 v = reinterpret_cast<const float4*>(in)[i];
        ushort4 p;
        p.x = bfb(v.x); p.y = bfb(v.y); p.z = bfb(v.z); p.w = bfb(v.w);
        reinterpret_cast<ushort4*>(out)[i] = p;
    }
}

// ---------------------------------------------------------------- fused QKV GEMM
// (unchanged — verified correct; attn remains the bottleneck)
__global__ __launch_bounds__(256) void gemm_qkv(
    const __hip_bfloat16* __restrict__ A,
    const __hip_bfloat16* __restrict__ Bw,
    const float* __restrict__ bq, const float* __restrict__ bk,
    const float* __restrict__ bv,
    __hip_bfloat16* __restrict__ Qb, __hip_bfloat16* __restrict__ Kb,
    __hip_bfloat16* __restrict__ VTb) {
    constexpr int Kd = DMODEL;
    __shared__ __hip_bfloat16 As[128 * 32];
    __shared__ __hip_bfloat16 Bs[128 * 32];
    const int tid = threadIdx.x;
    const int wave = tid >> 6, lane = tid & 63;
    const int lg = lane >> 4, lr = lane & 15;
    const int wr = wave >> 1, wc = wave & 1;
    const int by = blockIdx.y, bx = blockIdx.x;
    const __hip_bfloat16* Ab = A + (size_t)by * 128 * Kd;
    const __hip_bfloat16* Bb = Bw + (size_t)bx * 128 * Kd;
    f32x4 acc[4][4] = {};
    for (int kt = 0; kt < Kd / 32; ++kt) {
#pragma unroll
        for (int i = 0; i < 2; ++i) {
            int c = tid + i * 256;
            int row = c >> 2, c4 = c & 3;
            gload_lds16(Ab + (size_t)row * Kd + kt * 32 + c4 * 8, &As[c * 8]);
        }
#pragma unroll
        for (int i = 0; i < 2; ++i) {
            int c = tid + i * 256;
            int row = c >> 2, c4 = c & 3;
            gload_lds16(Bb + (size_t)row * Kd + kt * 32 + c4 * 8, &Bs[c * 8]);
        }
        __syncthreads();
        bf16x8 af[4], bfr[4];
#pragma unroll
        for (int m = 0; m < 4; ++m)
            af[m] = *(const bf16x8*)&As[(wr * 64 + m * 16 + lr) * 32 + lg * 8];
#pragma unroll
        for (int n = 0; n < 4; ++n)
            bfr[n] = *(const bf16x8*)&Bs[(wc * 64 + n * 16 + lr) * 32 + lg * 8];
#pragma unroll
        for (int m = 0; m < 4; ++m)
#pragma unroll
            for (int n = 0; n < 4; ++n)
                acc[m][n] = __builtin_amdgcn_mfma_f32_16x16x32_bf16(
                    af[m], bfr[n], acc[m][n], 0, 0, 0);
        __syncthreads();
    }
    const int sel = (bx * 128) >> 10;  // block-uniform 0/1/2
    const float* bp = sel == 0 ? bq : (sel == 1 ? bk : bv);
    __hip_bfloat16* dst = sel == 0 ? Qb : (sel == 1 ? Kb : VTb);
#pragma unroll
    for (int m = 0; m < 4; ++m)
#pragma unroll
        for (int n = 0; n < 4; ++n)
#pragma unroll
            for (int r = 0; r < 4; ++r) {
                int gm = by * 128 + wr * 64 + m * 16 + lg * 4 + r;
                int gn = bx * 128 + wc * 64 + n * 16 + lr;
                int nn = gn & (DMODEL - 1);
                float v = acc[m][n][r] + bp[nn];
                int bb = gm >> 11, l = gm & (LEN - 1);
                int h = nn >> 6, hd = nn & (HD - 1);
                size_t addr = (sel < 2)
                    ? ((((size_t)bb * NH + h) * LEN + l) * HD + hd)
                    : ((((size_t)bb * NH + h) * HD + hd) * LEN + l);
                dst[addr] = __float2bfloat16(v);
            }
}

// ---------------------------------------------------------------- flash attention
// grid: 1024 blocks 1D (XCD-swizzled). 4 waves x 16 q-rows. KVBLK=64, LDS dbuf.
// SWAPPED QK^T: s = mfma(K,Q) -> lane holds q-row (lr) x 16 keys in-register.
// Softmax: in-lane tree reduce + 2 shfl_xor; per-lane scalar m,l (base-2 domain);
// defer-max (THR=8) skips o-rescale on non-growing tiles.
#define SC 0.18033688f    // 0.125 * log2(e)
__global__ __launch_bounds__(256) void attn_fwd(
    const __hip_bfloat16* __restrict__ Qb,   // [BH][L][HD]
    const __hip_bfloat16* __restrict__ Kb,   // [BH][L][HD]
    const __hip_bfloat16* __restrict__ VTb,  // [BH][HD][L]
    __hip_bfloat16* __restrict__ Ob) {       // [B][L][D]
    const int lin = blockIdx.x;
    const int wg = (lin & 7) * 128 + (lin >> 3);   // bijective (1024 = 8*128)
    const int bh = wg >> 5;
    const int qt = wg & 31;
    const int b = bh >> 4, h = bh & (NH - 1);
    const int tid = threadIdx.x;
    const int wave = tid >> 6, lane = tid & 63;
    const int lg = lane >> 4, lr = lane & 15;
    const int sw = lr & 7;
    const int qw = qt * 64 + wave * 16;
    const __hip_bfloat16* Qp = Qb + ((size_t)bh * LEN + qw) * HD;
    const __hip_bfloat16* Kp = Kb + (size_t)bh * LEN * HD;
    const __hip_bfloat16* Vp = VTb + (size_t)bh * HD * LEN;

    __shared__ __hip_bfloat16 Ks[2][64 * 64];
    __shared__ __hip_bfloat16 Vs[2][64 * 64];
    __shared__ __hip_bfloat16 Plds[4][16][72];
    __hip_bfloat16* pl = &Plds[wave][0][0];

    const int c0 = tid, c1 = tid + 256;
    const int r0 = c0 >> 3, j0 = (c0 & 7) ^ (r0 & 7);
    const int r1 = c1 >> 3, j1 = (c1 & 7) ^ (r1 & 7);
    const __hip_bfloat16* kg0 = Kp + (size_t)r0 * HD + j0 * 8;
    const __hip_bfloat16* kg1 = Kp + (size_t)r1 * HD + j1 * 8;
    const __hip_bfloat16* vg0 = Vp + (size_t)r0 * LEN + j0 * 8;
    const __hip_bfloat16* vg1 = Vp + (size_t)r1 * LEN + j1 * 8;

    bf16x8 qf[2];
    qf[0] = *(const bf16x8*)(Qp + lr * HD + lg * 8);
    qf[1] = *(const bf16x8*)(Qp + lr * HD + 32 + lg * 8);

    float m_i = -INFINITY;   // per-lane scalar, q-row = lr, base-2 domain
    float l_i = 0.f;
    f32x4 o[4] = {};

    gload_lds16(kg0, &Ks[0][c0 * 8]);
    gload_lds16(kg1, &Ks[0][c1 * 8]);
    gload_lds16(vg0, &Vs[0][c0 * 8]);
    gload_lds16(vg1, &Vs[0][c1 * 8]);
    __syncthreads();

    constexpr int NT = LEN / 64;
    for (int kt = 0; kt < NT; ++kt) {
        const int cb = kt & 1, nb = cb ^ 1;
        if (kt + 1 < NT) {
            size_t ko = (size_t)(kt + 1) * 64 * HD;
            size_t vo = (size_t)(kt + 1) * 64;
            gload_lds16(kg0 + ko, &Ks[nb][c0 * 8]);
            gload_lds16(kg1 + ko, &Ks[nb][c1 * 8]);
            gload_lds16(vg0 + vo, &Vs[nb][c0 * 8]);
            gload_lds16(vg1 + vo, &Vs[nb][c1 * 8]);
        }
        const __hip_bfloat16* ks = Ks[cb];
        const __hip_bfloat16* vs = Vs[cb];
        // --- QK^T SWAPPED: s[n] reg r = score(key = n*16+lg*4+r, q = lr) ---
        f32x4 s[4] = {};
#pragma unroll
        for (int kk = 0; kk < 2; ++kk) {
#pragma unroll
            for (int n = 0; n < 4; ++n) {
                int krow = n * 16 + lr;
                bf16x8 kf = *(const bf16x8*)&ks[krow * 64 +
                                                (((kk << 2) + lg) ^ sw) * 8];
                s[n] = __builtin_amdgcn_mfma_f32_16x16x32_bf16(kf, qf[kk], s[n],
                                                               0, 0, 0);
            }
        }
        // --- online softmax, per-lane (q = lr), base-2 domain ---
        float t0 = fmaxf(fmaxf(s[0][0], s[0][1]), fmaxf(s[0][2], s[0][3]));
        float t1 = fmaxf(fmaxf(s[1][0], s[1][1]), fmaxf(s[1][2], s[1][3]));
        float t2 = fmaxf(fmaxf(s[2][0], s[2][1]), fmaxf(s[2][2], s[2][3]));
        float t3 = fmaxf(fmaxf(s[3][0], s[3][1]), fmaxf(s[3][2], s[3][3]));
        float tmax = fmaxf(fmaxf(t0, t1), fmaxf(t2, t3));
        tmax = fmaxf(tmax, __shfl_xor(tmax, 16, 64));
        tmax = fmaxf(tmax, __shfl_xor(tmax, 32, 64));
        float pmax = tmax * SC;
        if (__any(pmax > m_i + 8.f)) {   // defer-max: rescale only on real growth
            float mnew = fmaxf(m_i, pmax);
            float corr = exp2f(m_i - mnew);
            m_i = mnew;
            l_i *= corr;
#pragma unroll
            for (int r = 0; r < 4; ++r) {
                float cr = __shfl(corr, lg * 4 + r, 16);
#pragma unroll
                for (int n = 0; n < 4; ++n) o[n][r] *= cr;
            }
        }
        float p[4][4];
#pragma unroll
        for (int n = 0; n < 4; ++n)
#pragma unroll
            for (int r = 0; r < 4; ++r)
                p[n][r] = exp2f(s[n][r] * SC - m_i);
        float a0 = (p[0][0] + p[0][1]) + (p[0][2] + p[0][3]);
        float a1 = (p[1][0] + p[1][1]) + (p[1][2] + p[1][3]);
        float a2 = (p[2][0] + p[2][1]) + (p[2][2] + p[2][3]);
        float a3 = (p[3][0] + p[3][1]) + (p[3][2] + p[3][3]);
        float ps = (a0 + a1) + (a2 + a3);
        ps += __shfl_xor(ps, 16, 64);
        ps += __shfl_xor(ps, 32, 64);
        l_i += ps;
        // --- P -> per-wave LDS: row = q = lr, 4x ds_write_b64 ---
#pragma unroll
        for (int n = 0; n < 4; ++n) {
            ushort4 pk;
            pk.x = bfb(p[n][0]); pk.y = bfb(p[n][1]);
            pk.z = bfb(p[n][2]); pk.w = bfb(p[n][3]);
            *(ushort4*)&pl[lr * 72 + n * 16 + lg * 4] = pk;
        }
        asm volatile("" ::: "memory");
        // --- PV: O += P @ V (A-frag rows = q = lr; D rows = q = lg*4+r) ---
#pragma unroll
        for (int kk = 0; kk < 2; ++kk) {
            bf16x8 pa = *(const bf16x8*)&pl[lr * 72 + kk * 32 + lg * 8];
#pragma unroll
            for (int n = 0; n < 4; ++n) {
                int vrow = n * 16 + lr;
                bf16x8 vf = *(const bf16x8*)&vs[vrow * 64 +
                                                (((kk << 2) + lg) ^ sw) * 8];
                o[n] = __builtin_amdgcn_mfma_f32_16x16x32_bf16(pa, vf, o[n],
                                                               0, 0, 0);
            }
        }
        __syncthreads();
    }
#pragma unroll
    for (int r = 0; r < 4; ++r) {
        float lq = __shfl(l_i, lg * 4 + r, 16);
        float invq = 1.f / lq;
        int gq = qw + lg * 4 + r;
#pragma unroll
        for (int n = 0; n < 4; ++n) {
            int gd = h * HD + n * 16 + lr;
            Ob[((size_t)b * LEN + gq) * DMODEL + gd] =
                __float2bfloat16(o[n][r] * invq);
        }
    }
}

// ---------------------------------------------------------------- output GEMM
__global__ __launch_bounds__(256) void gemm_out(
    const __hip_bfloat16* __restrict__ A,    // [4096][1024]
    const __hip_bfloat16* __restrict__ Bw,   // [1024][1024]
    const float* __restrict__ bo, float* __restrict__ out) {
    constexpr int Kd = DMODEL, N = DMODEL;
    __shared__ __hip_bfloat16 As[64 * 32];
    __shared__ __hip_bfloat16 Bs[128 * 32];
    const int tid = threadIdx.x;
    const int wave = tid >> 6, lane = tid & 63;
    const int lg = lane >> 4, lr = lane & 15;
    const int wr = wave >> 1, wc = wave & 1;  // wave tile 32x64
    const int by = blockIdx.y, bx = blockIdx.x;
    const __hip_bfloat16* Ab = A + (size_t)by * 64 * Kd;
    const __hip_bfloat16* Bb = Bw + (size_t)bx * 128 * Kd;
    f32x4 acc[2][4] = {};
    for (int kt = 0; kt < Kd / 32; ++kt) {
        {
            int c = tid;
            int row = c >> 2, c4 = c & 3;
            gload_lds16(Ab + (size_t)row * Kd + kt * 32 + c4 * 8, &As[c * 8]);
        }
#pragma unroll
        for (int i = 0; i < 2; ++i) {
            int c = tid + i * 256;
            int row = c >> 2, c4 = c & 3;
            gload_lds16(Bb + (size_t)row * Kd + kt * 32 + c4 * 8, &Bs[c * 8]);
        }
        __syncthreads();
        bf16x8 af[2], bfr[4];
#pragma unroll
        for (int m = 0; m < 2; ++m)
            af[m] = *(const bf16x8*)&As[(wr * 32 + m * 16 + lr) * 32 + lg * 8];
#pragma unroll
        for (int n = 0; n < 4; ++n)
            bfr[n] = *(const bf16x8*)&Bs[(wc * 64 + n * 16 + lr) * 32 + lg * 8];
#pragma unroll
        for (int m = 0; m < 2; ++m)
#pragma unroll
            for (int n = 0; n < 4; ++n)
                acc[m][n] = __builtin_amdgcn_mfma_f32_16x16x32_bf16(
                    af[m], bfr[n], acc[m][n], 0, 0, 0);
        __syncthreads();
    }
#pragma unroll
    for (int m = 0; m < 2; ++m)
#pragma unroll
        for (int n = 0; n < 4; ++n)
#pragma unroll
            for (int r = 0; r < 4; ++r) {
                int gm = by * 64 + wr * 32 + m * 16 + lg * 4 + r;
                int gn = bx * 128 + wc * 64 + n * 16 + lr;
                out[(size_t)gm * N + gn] = acc[m][n][r] + bo[gn];
            }
}

// ---------------------------------------------------------------- launch
extern "C" void kernel_launch(void* const* d_in, const int* in_sizes, int n_in,
                              void* d_out, int out_size, void* d_ws, size_t ws_size,
                              hipStream_t stream) {
    const float* x  = (const float*)d_in[0];
    const float* wq = (const float*)d_in[1];
    const float* bq = (const float*)d_in[2];
    const float* wk = (const float*)d_in[3];
    const float* bk = (const float*)d_in[4];
    const float* wv = (const float*)d_in[5];
    const float* bv = (const float*)d_in[6];
    const float* wo = (const float*)d_in[7];
    const float* bo = (const float*)d_in[8];

    char* ws = (char*)d_ws;
    __hip_bfloat16* x_bf  = (__hip_bfloat16*)(ws);                    // 8 MB
    __hip_bfloat16* wqkv  = (__hip_bfloat16*)(ws + (8u  << 20));      // 6 MB
    __hip_bfloat16* wo_bf = (__hip_bfloat16*)(ws + (14u << 20));      // 2 MB
    __hip_bfloat16* Qb    = (__hip_bfloat16*)(ws + (16u << 20));      // 8 MB
    __hip_bfloat16* Kb    = (__hip_bfloat16*)(ws + (24u << 20));      // 8 MB
    __hip_bfloat16* VTb   = (__hip_bfloat16*)(ws + (32u << 20));      // 8 MB
    __hip_bfloat16* Ob    = (__hip_bfloat16*)(ws + (40u << 20));      // 8 MB

    cast_f32_bf16_k<<<1024, 256, 0, stream>>>(x, x_bf, (MROWS * DMODEL) / 4);
    cast_f32_bf16_k<<<512, 256, 0, stream>>>(wq, wqkv, (DMODEL * DMODEL) / 4);
    cast_f32_bf16_k<<<512, 256, 0, stream>>>(wk, wqkv + (1u << 20), (DMODEL * DMODEL) / 4);
    cast_f32_bf16_k<<<512, 256, 0, stream>>>(wv, wqkv + (2u << 20), (DMODEL * DMODEL) / 4);
    cast_f32_bf16_k<<<512, 256, 0, stream>>>(wo, wo_bf, (DMODEL * DMODEL) / 4);

    gemm_qkv<<<dim3(24, 32), 256, 0, stream>>>(x_bf, wqkv, bq, bk, bv, Qb, Kb, VTb);
    attn_fwd<<<1024, 256, 0, stream>>>(Qb, Kb, VTb, Ob);
    gemm_out<<<dim3(8, 64), 256, 0, stream>>>(Ob, wo_bf, bo, (float*)d_out);
}

// Round 6
// 222.571 us; speedup vs baseline: 1.9577x; 1.1017x over previous
//
#include <hip/hip_runtime.h>
#include <hip/hip_bf16.h>
#include <cstdint>

// Problem constants: B=2, L=2048, D=1024, H=16, HD=64
#define LEN   2048
#define DMODEL 1024
#define NH    16
#define HD    64
#define BH    32          // B*NH
#define MROWS 4096        // B*LEN

typedef __attribute__((ext_vector_type(8))) short bf16x8;
typedef __attribute__((ext_vector_type(4))) float f32x4;
typedef unsigned int u32;

__device__ __forceinline__ void gload_lds16(const void* g, void* l) {
    __builtin_amdgcn_global_load_lds(
        (const __attribute__((address_space(1))) u32*)g,
        (__attribute__((address_space(3))) u32*)l, 16, 0, 0);
}

__device__ __forceinline__ unsigned short bfb(float f) {
    __hip_bfloat16 h = __float2bfloat16(f);
    return *reinterpret_cast<unsigned short*>(&h);
}

// ---------------------------------------------------------------- cast f32->bf16
__global__ void cast_f32_bf16_k(const float* __restrict__ in,
                                __hip_bfloat16* __restrict__ out, int n4) {
    int stride = gridDim.x * blockDim.x;
    for (int i = blockIdx.x * blockDim.x + threadIdx.x; i < n4; i += stride) {
        float4 v = reinterpret_cast<const float4*>(in)[i];
        ushort4 p;
        p.x = bfb(v.x); p.y = bfb(v.y); p.z = bfb(v.z); p.w = bfb(v.w);
        reinterpret_cast<ushort4*>(out)[i] = p;
    }
}

// ---------------------------------------------------------------- fused QKV GEMM
// (unchanged — verified correct)
__global__ __launch_bounds__(256) void gemm_qkv(
    const __hip_bfloat16* __restrict__ A,
    const __hip_bfloat16* __restrict__ Bw,
    const float* __restrict__ bq, const float* __restrict__ bk,
    const float* __restrict__ bv,
    __hip_bfloat16* __restrict__ Qb, __hip_bfloat16* __restrict__ Kb,
    __hip_bfloat16* __restrict__ VTb) {
    constexpr int Kd = DMODEL;
    __shared__ __hip_bfloat16 As[128 * 32];
    __shared__ __hip_bfloat16 Bs[128 * 32];
    const int tid = threadIdx.x;
    const int wave = tid >> 6, lane = tid & 63;
    const int lg = lane >> 4, lr = lane & 15;
    const int wr = wave >> 1, wc = wave & 1;
    const int by = blockIdx.y, bx = blockIdx.x;
    const __hip_bfloat16* Ab = A + (size_t)by * 128 * Kd;
    const __hip_bfloat16* Bb = Bw + (size_t)bx * 128 * Kd;
    f32x4 acc[4][4] = {};
    for (int kt = 0; kt < Kd / 32; ++kt) {
#pragma unroll
        for (int i = 0; i < 2; ++i) {
            int c = tid + i * 256;
            int row = c >> 2, c4 = c & 3;
            gload_lds16(Ab + (size_t)row * Kd + kt * 32 + c4 * 8, &As[c * 8]);
        }
#pragma unroll
        for (int i = 0; i < 2; ++i) {
            int c = tid + i * 256;
            int row = c >> 2, c4 = c & 3;
            gload_lds16(Bb + (size_t)row * Kd + kt * 32 + c4 * 8, &Bs[c * 8]);
        }
        __syncthreads();
        bf16x8 af[4], bfr[4];
#pragma unroll
        for (int m = 0; m < 4; ++m)
            af[m] = *(const bf16x8*)&As[(wr * 64 + m * 16 + lr) * 32 + lg * 8];
#pragma unroll
        for (int n = 0; n < 4; ++n)
            bfr[n] = *(const bf16x8*)&Bs[(wc * 64 + n * 16 + lr) * 32 + lg * 8];
#pragma unroll
        for (int m = 0; m < 4; ++m)
#pragma unroll
            for (int n = 0; n < 4; ++n)
                acc[m][n] = __builtin_amdgcn_mfma_f32_16x16x32_bf16(
                    af[m], bfr[n], acc[m][n], 0, 0, 0);
        __syncthreads();
    }
    const int sel = (bx * 128) >> 10;  // block-uniform 0/1/2
    const float* bp = sel == 0 ? bq : (sel == 1 ? bk : bv);
    __hip_bfloat16* dst = sel == 0 ? Qb : (sel == 1 ? Kb : VTb);
#pragma unroll
    for (int m = 0; m < 4; ++m)
#pragma unroll
        for (int n = 0; n < 4; ++n)
#pragma unroll
            for (int r = 0; r < 4; ++r) {
                int gm = by * 128 + wr * 64 + m * 16 + lg * 4 + r;
                int gn = bx * 128 + wc * 64 + n * 16 + lr;
                int nn = gn & (DMODEL - 1);
                float v = acc[m][n][r] + bp[nn];
                int bb = gm >> 11, l = gm & (LEN - 1);
                int h = nn >> 6, hd = nn & (HD - 1);
                size_t addr = (sel < 2)
                    ? ((((size_t)bb * NH + h) * LEN + l) * HD + hd)
                    : ((((size_t)bb * NH + h) * HD + hd) * LEN + l);
                dst[addr] = __float2bfloat16(v);
            }
}

// ---------------------------------------------------------------- flash attention
// grid: 512 blocks 1D (XCD-swizzled). 8 waves x 16 q-rows = 128 q/block, KVBLK=64.
// One K/V staging unit serves 8 waves (staging per score halved vs 4-wave);
// LDS 51.2KB -> 3 blocks/CU = 24 waves/CU. Swapped QK^T in-register softmax,
// defer-max, T5 setprio around MFMA clusters.
#define SC 0.18033688f    // 0.125 * log2(e)
__global__ __launch_bounds__(512) void attn_fwd(
    const __hip_bfloat16* __restrict__ Qb,   // [BH][L][HD]
    const __hip_bfloat16* __restrict__ Kb,   // [BH][L][HD]
    const __hip_bfloat16* __restrict__ VTb,  // [BH][HD][L]
    __hip_bfloat16* __restrict__ Ob) {       // [B][L][D]
    const int lin = blockIdx.x;
    const int wg = (lin & 7) * 64 + (lin >> 3);   // bijective (512 = 8*64)
    const int bh = wg >> 4;          // 0..31
    const int qt = wg & 15;          // 0..15 (128-row q tiles)
    const int b = bh >> 4, h = bh & (NH - 1);
    const int tid = threadIdx.x;
    const int wave = tid >> 6, lane = tid & 63;
    const int lg = lane >> 4, lr = lane & 15;
    const int sw = lr & 7;
    const int qw = qt * 128 + wave * 16;
    const __hip_bfloat16* Qp = Qb + ((size_t)bh * LEN + qw) * HD;
    const __hip_bfloat16* Kp = Kb + (size_t)bh * LEN * HD;
    const __hip_bfloat16* Vp = VTb + (size_t)bh * HD * LEN;

    __shared__ __hip_bfloat16 Ks[2][64 * 64];
    __shared__ __hip_bfloat16 Vs[2][64 * 64];
    __shared__ __hip_bfloat16 Plds[8][16][72];
    __hip_bfloat16* pl = &Plds[wave][0][0];

    // staging: 512 chunks of 16B per tile; each thread owns 1 K chunk + 1 V chunk
    const int c0 = tid;
    const int r0 = c0 >> 3, j0 = (c0 & 7) ^ (r0 & 7);
    const __hip_bfloat16* kg0 = Kp + (size_t)r0 * HD + j0 * 8;
    const __hip_bfloat16* vg0 = Vp + (size_t)r0 * LEN + j0 * 8;

    bf16x8 qf[2];
    qf[0] = *(const bf16x8*)(Qp + lr * HD + lg * 8);
    qf[1] = *(const bf16x8*)(Qp + lr * HD + 32 + lg * 8);

    float m_i = -INFINITY;   // per-lane scalar, q-row = lr, base-2 domain
    float l_i = 0.f;
    f32x4 o[4] = {};

    gload_lds16(kg0, &Ks[0][c0 * 8]);
    gload_lds16(vg0, &Vs[0][c0 * 8]);
    __syncthreads();

    constexpr int NT = LEN / 64;
    for (int kt = 0; kt < NT; ++kt) {
        const int cb = kt & 1, nb = cb ^ 1;
        if (kt + 1 < NT) {
            size_t ko = (size_t)(kt + 1) * 64 * HD;
            size_t vo = (size_t)(kt + 1) * 64;
            gload_lds16(kg0 + ko, &Ks[nb][c0 * 8]);
            gload_lds16(vg0 + vo, &Vs[nb][c0 * 8]);
        }
        const __hip_bfloat16* ks = Ks[cb];
        const __hip_bfloat16* vs = Vs[cb];
        // --- QK^T SWAPPED: s[n] reg r = score(key = n*16+lg*4+r, q = lr) ---
        f32x4 s[4] = {};
        __builtin_amdgcn_s_setprio(1);
#pragma unroll
        for (int kk = 0; kk < 2; ++kk) {
#pragma unroll
            for (int n = 0; n < 4; ++n) {
                int krow = n * 16 + lr;
                bf16x8 kf = *(const bf16x8*)&ks[krow * 64 +
                                                (((kk << 2) + lg) ^ sw) * 8];
                s[n] = __builtin_amdgcn_mfma_f32_16x16x32_bf16(kf, qf[kk], s[n],
                                                               0, 0, 0);
            }
        }
        __builtin_amdgcn_s_setprio(0);
        // --- online softmax, per-lane (q = lr), base-2 domain ---
        float t0 = fmaxf(fmaxf(s[0][0], s[0][1]), fmaxf(s[0][2], s[0][3]));
        float t1 = fmaxf(fmaxf(s[1][0], s[1][1]), fmaxf(s[1][2], s[1][3]));
        float t2 = fmaxf(fmaxf(s[2][0], s[2][1]), fmaxf(s[2][2], s[2][3]));
        float t3 = fmaxf(fmaxf(s[3][0], s[3][1]), fmaxf(s[3][2], s[3][3]));
        float tmax = fmaxf(fmaxf(t0, t1), fmaxf(t2, t3));
        tmax = fmaxf(tmax, __shfl_xor(tmax, 16, 64));
        tmax = fmaxf(tmax, __shfl_xor(tmax, 32, 64));
        float pmax = tmax * SC;
        if (__any(pmax > m_i + 8.f)) {   // defer-max: rescale only on real growth
            float mnew = fmaxf(m_i, pmax);
            float corr = exp2f(m_i - mnew);
            m_i = mnew;
            l_i *= corr;
#pragma unroll
            for (int r = 0; r < 4; ++r) {
                float cr = __shfl(corr, lg * 4 + r, 16);
#pragma unroll
                for (int n = 0; n < 4; ++n) o[n][r] *= cr;
            }
        }
        float p[4][4];
#pragma unroll
        for (int n = 0; n < 4; ++n)
#pragma unroll
            for (int r = 0; r < 4; ++r)
                p[n][r] = exp2f(s[n][r] * SC - m_i);
        float a0 = (p[0][0] + p[0][1]) + (p[0][2] + p[0][3]);
        float a1 = (p[1][0] + p[1][1]) + (p[1][2] + p[1][3]);
        float a2 = (p[2][0] + p[2][1]) + (p[2][2] + p[2][3]);
        float a3 = (p[3][0] + p[3][1]) + (p[3][2] + p[3][3]);
        float ps = (a0 + a1) + (a2 + a3);
        ps += __shfl_xor(ps, 16, 64);
        ps += __shfl_xor(ps, 32, 64);
        l_i += ps;
        // --- P -> per-wave LDS: row = q = lr, 4x ds_write_b64 ---
#pragma unroll
        for (int n = 0; n < 4; ++n) {
            ushort4 pk;
            pk.x = bfb(p[n][0]); pk.y = bfb(p[n][1]);
            pk.z = bfb(p[n][2]); pk.w = bfb(p[n][3]);
            *(ushort4*)&pl[lr * 72 + n * 16 + lg * 4] = pk;
        }
        asm volatile("" ::: "memory");
        // --- PV: O += P @ V (A-frag rows = q = lr; D rows = q = lg*4+r) ---
        __builtin_amdgcn_s_setprio(1);
#pragma unroll
        for (int kk = 0; kk < 2; ++kk) {
            bf16x8 pa = *(const bf16x8*)&pl[lr * 72 + kk * 32 + lg * 8];
#pragma unroll
            for (int n = 0; n < 4; ++n) {
                int vrow = n * 16 + lr;
                bf16x8 vf = *(const bf16x8*)&vs[vrow * 64 +
                                                (((kk << 2) + lg) ^ sw) * 8];
                o[n] = __builtin_amdgcn_mfma_f32_16x16x32_bf16(pa, vf, o[n],
                                                               0, 0, 0);
            }
        }
        __builtin_amdgcn_s_setprio(0);
        __syncthreads();
    }
#pragma unroll
    for (int r = 0; r < 4; ++r) {
        float lq = __shfl(l_i, lg * 4 + r, 16);
        float invq = 1.f / lq;
        int gq = qw + lg * 4 + r;
#pragma unroll
        for (int n = 0; n < 4; ++n) {
            int gd = h * HD + n * 16 + lr;
            Ob[((size_t)b * LEN + gq) * DMODEL + gd] =
                __float2bfloat16(o[n][r] * invq);
        }
    }
}

// ---------------------------------------------------------------- output GEMM
__global__ __launch_bounds__(256) void gemm_out(
    const __hip_bfloat16* __restrict__ A,    // [4096][1024]
    const __hip_bfloat16* __restrict__ Bw,   // [1024][1024]
    const float* __restrict__ bo, float* __restrict__ out) {
    constexpr int Kd = DMODEL, N = DMODEL;
    __shared__ __hip_bfloat16 As[64 * 32];
    __shared__ __hip_bfloat16 Bs[128 * 32];
    const int tid = threadIdx.x;
    const int wave = tid >> 6, lane = tid & 63;
    const int lg = lane >> 4, lr = lane & 15;
    const int wr = wave >> 1, wc = wave & 1;  // wave tile 32x64
    const int by = blockIdx.y, bx = blockIdx.x;
    const __hip_bfloat16* Ab = A + (size_t)by * 64 * Kd;
    const __hip_bfloat16* Bb = Bw + (size_t)bx * 128 * Kd;
    f32x4 acc[2][4] = {};
    for (int kt = 0; kt < Kd / 32; ++kt) {
        {
            int c = tid;
            int row = c >> 2, c4 = c & 3;
            gload_lds16(Ab + (size_t)row * Kd + kt * 32 + c4 * 8, &As[c * 8]);
        }
#pragma unroll
        for (int i = 0; i < 2; ++i) {
            int c = tid + i * 256;
            int row = c >> 2, c4 = c & 3;
            gload_lds16(Bb + (size_t)row * Kd + kt * 32 + c4 * 8, &Bs[c * 8]);
        }
        __syncthreads();
        bf16x8 af[2], bfr[4];
#pragma unroll
        for (int m = 0; m < 2; ++m)
            af[m] = *(const bf16x8*)&As[(wr * 32 + m * 16 + lr) * 32 + lg * 8];
#pragma unroll
        for (int n = 0; n < 4; ++n)
            bfr[n] = *(const bf16x8*)&Bs[(wc * 64 + n * 16 + lr) * 32 + lg * 8];
#pragma unroll
        for (int m = 0; m < 2; ++m)
#pragma unroll
            for (int n = 0; n < 4; ++n)
                acc[m][n] = __builtin_amdgcn_mfma_f32_16x16x32_bf16(
                    af[m], bfr[n], acc[m][n], 0, 0, 0);
        __syncthreads();
    }
#pragma unroll
    for (int m = 0; m < 2; ++m)
#pragma unroll
        for (int n = 0; n < 4; ++n)
#pragma unroll
            for (int r = 0; r < 4; ++r) {
                int gm = by * 64 + wr * 32 + m * 16 + lg * 4 + r;
                int gn = bx * 128 + wc * 64 + n * 16 + lr;
                out[(size_t)gm * N + gn] = acc[m][n][r] + bo[gn];
            }
}

// ---------------------------------------------------------------- launch
extern "C" void kernel_launch(void* const* d_in, const int* in_sizes, int n_in,
                              void* d_out, int out_size, void* d_ws, size_t ws_size,
                              hipStream_t stream) {
    const float* x  = (const float*)d_in[0];
    const float* wq = (const float*)d_in[1];
    const float* bq = (const float*)d_in[2];
    const float* wk = (const float*)d_in[3];
    const float* bk = (const float*)d_in[4];
    const float* wv = (const float*)d_in[5];
    const float* bv = (const float*)d_in[6];
    const float* wo = (const float*)d_in[7];
    const float* bo = (const float*)d_in[8];

    char* ws = (char*)d_ws;
    __hip_bfloat16* x_bf  = (__hip_bfloat16*)(ws);                    // 8 MB
    __hip_bfloat16* wqkv  = (__hip_bfloat16*)(ws + (8u  << 20));      // 6 MB
    __hip_bfloat16* wo_bf = (__hip_bfloat16*)(ws + (14u << 20));      // 2 MB
    __hip_bfloat16* Qb    = (__hip_bfloat16*)(ws + (16u << 20));      // 8 MB
    __hip_bfloat16* Kb    = (__hip_bfloat16*)(ws + (24u << 20));      // 8 MB
    __hip_bfloat16* VTb   = (__hip_bfloat16*)(ws + (32u << 20));      // 8 MB
    __hip_bfloat16* Ob    = (__hip_bfloat16*)(ws + (40u << 20));      // 8 MB

    cast_f32_bf16_k<<<1024, 256, 0, stream>>>(x, x_bf, (MROWS * DMODEL) / 4);
    cast_f32_bf16_k<<<512, 256, 0, stream>>>(wq, wqkv, (DMODEL * DMODEL) / 4);
    cast_f32_bf16_k<<<512, 256, 0, stream>>>(wk, wqkv + (1u << 20), (DMODEL * DMODEL) / 4);
    cast_f32_bf16_k<<<512, 256, 0, stream>>>(wv, wqkv + (2u << 20), (DMODEL * DMODEL) / 4);
    cast_f32_bf16_k<<<512, 256, 0, stream>>>(wo, wo_bf, (DMODEL * DMODEL) / 4);

    gemm_qkv<<<dim3(24, 32), 256, 0, stream>>>(x_bf, wqkv, bq, bk, bv, Qb, Kb, VTb);
    attn_fwd<<<512, 512, 0, stream>>>(Qb, Kb, VTb, Ob);
    gemm_out<<<dim3(8, 64), 256, 0, stream>>>(Ob, wo_bf, bo, (float*)d_out);
}